// Round 1
// baseline (250.487 us; speedup 1.0000x reference)
//
#include <hip/hip_runtime.h>

#define RADIUS 32
#define STRIDE 16
#define HLO 63            // (1024-32)/16+1
#define HFULL 1024
#define GF_EPS 1e-4f
#define LOPLANE (HLO*HLO) // 3969

// ---------------- Stage 1+2: window stats + 3x3 inverse -> A,b planes -------
// grid: B*HLO*HLO blocks of 256 threads. Window = 32x32 at (ly*16, lx*16).
__global__ __launch_bounds__(256) void gf_stats_kernel(
    const float* __restrict__ guide, const float* __restrict__ src,
    const float* __restrict__ w1, float* __restrict__ ab /* [B][12][63][63] */)
{
    int bid = blockIdx.x;
    int lx = bid % HLO;
    int t  = bid / HLO;
    int ly = t % HLO;
    int b  = t / HLO;
    int tid = threadIdx.x;

    const size_t plane = (size_t)HFULL * HFULL;
    const float* g0 = guide + (size_t)b * 3 * plane;
    const float* s0 = src   + (size_t)b * 3 * plane;

    const int oy = ly * STRIDE, ox = lx * STRIDE;

    float acc[22];
#pragma unroll
    for (int i = 0; i < 22; i++) acc[i] = 0.f;

#pragma unroll
    for (int k = 0; k < 4; k++) {
        int p = k * 256 + tid;
        int r = p >> 5, c = p & 31;
        size_t off = (size_t)(oy + r) * HFULL + (ox + c);
        float gr = g0[off];
        float gg = g0[plane + off];
        float gb = g0[2 * plane + off];
        float pr = s0[off];
        float pg = s0[plane + off];
        float pb = s0[2 * plane + off];
        float w  = w1[p];
        acc[0] += gr;  acc[1] += gg;  acc[2] += gb;
        acc[3] += pr;  acc[4] += pg;  acc[5] += pb;
        acc[6]  += gr * pr;  acc[7]  += gr * pg;  acc[8]  += gr * pb;
        acc[9]  += gg * pr;  acc[10] += gg * pg;  acc[11] += gg * pb;
        acc[12] += gb * pr;  acc[13] += gb * pg;  acc[14] += gb * pb;
        acc[15] += w * gr * gr;  acc[16] += w * gr * gg;  acc[17] += w * gr * gb;
        acc[18] += w * gg * gg;  acc[19] += w * gg * gb;  acc[20] += w * gb * gb;
        acc[21] += w;
    }

    // wave (64-lane) butterfly reduce of all 22 accumulators
#pragma unroll
    for (int off = 32; off > 0; off >>= 1) {
#pragma unroll
        for (int i = 0; i < 22; i++)
            acc[i] += __shfl_down(acc[i], off, 64);
    }

    __shared__ float red[4][22];
    int wave = tid >> 6, lane = tid & 63;
    if (lane == 0) {
#pragma unroll
        for (int i = 0; i < 22; i++) red[wave][i] = acc[i];
    }
    __syncthreads();

    if (tid == 0) {
        float s[22];
#pragma unroll
        for (int i = 0; i < 22; i++)
            s[i] = red[0][i] + red[1][i] + red[2][i] + red[3][i];

        float N = s[21];
        float inv_n = 1.f / N;
        float mI[3] = { s[0] * inv_n, s[1] * inv_n, s[2] * inv_n };
        float mp[3] = { s[3] * inv_n, s[4] * inv_n, s[5] * inv_n };

        float cov[3][3];
#pragma unroll
        for (int i = 0; i < 3; i++)
#pragma unroll
            for (int c = 0; c < 3; c++)
                cov[i][c] = s[6 + i * 3 + c] * inv_n - mI[i] * mp[c];

        float v_rr = s[15] * inv_n - mI[0] * mI[0] + GF_EPS;
        float v_rg = s[16] * inv_n - mI[0] * mI[1];
        float v_rb = s[17] * inv_n - mI[0] * mI[2];
        float v_gg = s[18] * inv_n - mI[1] * mI[1] + GF_EPS;
        float v_gb = s[19] * inv_n - mI[1] * mI[2];
        float v_bb = s[20] * inv_n - mI[2] * mI[2] + GF_EPS;

        float det = v_rr * v_gg * v_bb + v_rg * v_gb * v_rb + v_rb * v_rg * v_gb
                  - v_rb * v_gg * v_rb - v_rg * v_rg * v_bb - v_rr * v_gb * v_gb;
        float invdet = 1.f / det;

        float i_rr =  (v_gg * v_bb - v_gb * v_gb) * invdet;
        float i_rg = -(v_rg * v_bb - v_rb * v_gb) * invdet;
        float i_rb =  (v_rg * v_gb - v_rb * v_gg) * invdet;
        float i_gg =  (v_rr * v_bb - v_rb * v_rb) * invdet;
        float i_gb = -(v_rr * v_gb - v_rb * v_rg) * invdet;
        float i_bb =  (v_rr * v_gg - v_rg * v_rg) * invdet;

        float inv[3][3] = { { i_rr, i_rg, i_rb },
                            { i_rg, i_gg, i_gb },
                            { i_rb, i_gb, i_bb } };

        // A[j][c] = sum_i inv_sigma[i][j] * cov[i][c]  (inv symmetric)
        float A[3][3];
#pragma unroll
        for (int j = 0; j < 3; j++)
#pragma unroll
            for (int c = 0; c < 3; c++)
                A[j][c] = inv[j][0] * cov[0][c] + inv[j][1] * cov[1][c] + inv[j][2] * cov[2][c];

        float bb_[3];
#pragma unroll
        for (int c = 0; c < 3; c++)
            bb_[c] = mp[c] - A[0][c] * mI[0] - A[1][c] * mI[1] - A[2][c] * mI[2];

        float* outp = ab + (size_t)b * 12 * LOPLANE + ly * HLO + lx;
#pragma unroll
        for (int j = 0; j < 3; j++)
#pragma unroll
            for (int c = 0; c < 3; c++)
                outp[(j * 3 + c) * LOPLANE] = A[j][c];
#pragma unroll
        for (int c = 0; c < 3; c++)
            outp[(9 + c) * LOPLANE] = bb_[c];
    }
}

// ---------------- Stage 3: bilinear upsample of A,b + apply to guide --------
// one thread per (b, y, x) output pixel, all 3 channels.
__global__ __launch_bounds__(256) void gf_apply_kernel(
    const float* __restrict__ guide, const float* __restrict__ ab,
    float* __restrict__ out)
{
    int idx = blockIdx.x * 256 + threadIdx.x;   // 8 * 1024 * 1024 threads
    int b   = idx >> 20;
    int rem = idx & ((1 << 20) - 1);
    int y   = rem >> 10;
    int x   = rem & 1023;

    const float scale = 62.0f / 1023.0f;
    float ty = (float)y * scale;
    float tx = (float)x * scale;
    int y0 = (int)ty;  if (y0 > 61) y0 = 61;   // guard fp edge: keep y1<=62
    int x0 = (int)tx;  if (x0 > 61) x0 = 61;
    int y1 = y0 + 1;
    int x1 = x0 + 1;
    float wy = ty - (float)y0;
    float wx = tx - (float)x0;

    const float* abb = ab + (size_t)b * 12 * LOPLANE;
    int i00 = y0 * HLO + x0;
    int i01 = y0 * HLO + x1;
    int i10 = y1 * HLO + x0;
    int i11 = y1 * HLO + x1;

    float Av[12];
#pragma unroll
    for (int j = 0; j < 12; j++) {
        const float* p = abb + j * LOPLANE;
        float a00 = p[i00], a01 = p[i01], a10 = p[i10], a11 = p[i11];
        float r0 = a00 * (1.f - wy) + a10 * wy;
        float r1 = a01 * (1.f - wy) + a11 * wy;
        Av[j] = r0 * (1.f - wx) + r1 * wx;
    }

    const size_t plane = (size_t)HFULL * HFULL;
    size_t goff = (size_t)b * 3 * plane + ((size_t)y << 10) + x;
    float gr = guide[goff];
    float gg = guide[goff + plane];
    float gb = guide[goff + 2 * plane];

#pragma unroll
    for (int c = 0; c < 3; c++) {
        float v = Av[0 + c] * gr + Av[3 + c] * gg + Av[6 + c] * gb + Av[9 + c];
        out[goff + (size_t)c * plane] = v;
    }
}

extern "C" void kernel_launch(void* const* d_in, const int* in_sizes, int n_in,
                              void* d_out, int out_size, void* d_ws, size_t ws_size,
                              hipStream_t stream) {
    const float* guide = (const float*)d_in[0];
    const float* src   = (const float*)d_in[1];
    const float* w1    = (const float*)d_in[2];
    // d_in[3] = w3 is all-ones by construction; box3 == plain window sum.
    float* out = (float*)d_out;
    float* ab  = (float*)d_ws;   // needs 8*12*3969*4 = 1.52 MB

    const int B = 8;
    int nblocks_stats = B * HLO * HLO;            // 31752
    gf_stats_kernel<<<nblocks_stats, 256, 0, stream>>>(guide, src, w1, ab);

    int nblocks_apply = (B * HFULL * HFULL) / 256; // 32768
    gf_apply_kernel<<<nblocks_apply, 256, 0, stream>>>(guide, ab, out);
}

// Round 2
// 248.671 us; speedup vs baseline: 1.0073x; 1.0073x over previous
//
#include <hip/hip_runtime.h>

#define RADIUS 32
#define STRIDE 16
#define HLO 63            // (1024-32)/16+1
#define HFULL 1024
#define GF_EPS 1e-4f
#define LOPLANE (HLO*HLO) // 3969
#define TILE 32           // ceil(63/2) window-tiles per dim
#define REG 48            // staged region: 2x2 windows at stride 16
#define RPLANE (REG*REG)  // 2304

// ---------------- Stage 1+2: 2x2 windows per block via LDS tile -------------
// grid: B*32*32 blocks of 256 threads (4 waves = 4 windows).
__global__ __launch_bounds__(256) void gf_stats2(
    const float* __restrict__ guide, const float* __restrict__ src,
    const float* __restrict__ w1, float* __restrict__ ab /* [B][12][63][63] */)
{
    __shared__ float lds[6 * RPLANE];   // 55.3 KB
    __shared__ float w1s[1024];         // 4 KB

    int bid = blockIdx.x;
    int tx = bid % TILE;
    int t  = bid / TILE;
    int ty = t % TILE;
    int b  = t / TILE;
    int tid = threadIdx.x;

    const size_t plane = (size_t)HFULL * HFULL;
    const float* g0 = guide + (size_t)b * 3 * plane;
    const float* s0 = src   + (size_t)b * 3 * plane;

    const int ry = 32 * ty, rx = 32 * tx;

    // stage w1 (1024 floats)
    {
        float4 v = reinterpret_cast<const float4*>(w1)[tid];
        reinterpret_cast<float4*>(w1s)[tid] = v;
    }

    // stage 6 planes of the 48x48 region, float4, zero-fill out of range
#pragma unroll
    for (int pl = 0; pl < 6; pl++) {
        const float* gp = (pl < 3) ? (g0 + (size_t)pl * plane)
                                   : (s0 + (size_t)(pl - 3) * plane);
#pragma unroll
        for (int ii = 0; ii < 3; ii++) {
            int i = ii * 256 + tid;
            if (i < 576) {
                int row = i / 12, c4 = (i % 12) * 4;
                int gy = ry + row, gx = rx + c4;
                float4 v = make_float4(0.f, 0.f, 0.f, 0.f);
                if (gy < HFULL && gx < HFULL)
                    v = *reinterpret_cast<const float4*>(gp + (size_t)gy * HFULL + gx);
                *reinterpret_cast<float4*>(&lds[pl * RPLANE + row * REG + c4]) = v;
            }
        }
    }
    __syncthreads();

    int wave = tid >> 6, lane = tid & 63;
    int wy = wave >> 1, wx = wave & 1;
    int wly = 2 * ty + wy, wlx = 2 * tx + wx;
    if (wly >= HLO || wlx >= HLO) return;

    const int r0 = 16 * wy, c0 = 16 * wx;

    float acc[22];
#pragma unroll
    for (int i = 0; i < 22; i++) acc[i] = 0.f;

#pragma unroll
    for (int k = 0; k < 16; k++) {
        int p = k * 64 + lane;
        int r = p >> 5, c = p & 31;
        int idx = (r0 + r) * REG + (c0 + c);
        float gr = lds[idx];
        float gg = lds[RPLANE + idx];
        float gb = lds[2 * RPLANE + idx];
        float pr = lds[3 * RPLANE + idx];
        float pg = lds[4 * RPLANE + idx];
        float pb = lds[5 * RPLANE + idx];
        float w  = w1s[p];
        acc[0] += gr;  acc[1] += gg;  acc[2] += gb;
        acc[3] += pr;  acc[4] += pg;  acc[5] += pb;
        acc[6]  += gr * pr;  acc[7]  += gr * pg;  acc[8]  += gr * pb;
        acc[9]  += gg * pr;  acc[10] += gg * pg;  acc[11] += gg * pb;
        acc[12] += gb * pr;  acc[13] += gb * pg;  acc[14] += gb * pb;
        acc[15] += w * gr * gr;  acc[16] += w * gr * gg;  acc[17] += w * gr * gb;
        acc[18] += w * gg * gg;  acc[19] += w * gg * gb;  acc[20] += w * gb * gb;
        acc[21] += w;
    }

    // wave-local butterfly reduce (64 lanes)
#pragma unroll
    for (int off = 1; off <= 32; off <<= 1) {
#pragma unroll
        for (int i = 0; i < 22; i++)
            acc[i] += __shfl_xor(acc[i], off, 64);
    }

    if (lane == 0) {
        float N = acc[21];
        float inv_n = 1.f / N;
        float mI[3] = { acc[0] * inv_n, acc[1] * inv_n, acc[2] * inv_n };
        float mp[3] = { acc[3] * inv_n, acc[4] * inv_n, acc[5] * inv_n };

        float cov[3][3];
#pragma unroll
        for (int i = 0; i < 3; i++)
#pragma unroll
            for (int c = 0; c < 3; c++)
                cov[i][c] = acc[6 + i * 3 + c] * inv_n - mI[i] * mp[c];

        float v_rr = acc[15] * inv_n - mI[0] * mI[0] + GF_EPS;
        float v_rg = acc[16] * inv_n - mI[0] * mI[1];
        float v_rb = acc[17] * inv_n - mI[0] * mI[2];
        float v_gg = acc[18] * inv_n - mI[1] * mI[1] + GF_EPS;
        float v_gb = acc[19] * inv_n - mI[1] * mI[2];
        float v_bb = acc[20] * inv_n - mI[2] * mI[2] + GF_EPS;

        float det = v_rr * v_gg * v_bb + v_rg * v_gb * v_rb + v_rb * v_rg * v_gb
                  - v_rb * v_gg * v_rb - v_rg * v_rg * v_bb - v_rr * v_gb * v_gb;
        float invdet = 1.f / det;

        float i_rr =  (v_gg * v_bb - v_gb * v_gb) * invdet;
        float i_rg = -(v_rg * v_bb - v_rb * v_gb) * invdet;
        float i_rb =  (v_rg * v_gb - v_rb * v_gg) * invdet;
        float i_gg =  (v_rr * v_bb - v_rb * v_rb) * invdet;
        float i_gb = -(v_rr * v_gb - v_rb * v_rg) * invdet;
        float i_bb =  (v_rr * v_gg - v_rg * v_rg) * invdet;

        float inv[3][3] = { { i_rr, i_rg, i_rb },
                            { i_rg, i_gg, i_gb },
                            { i_rb, i_gb, i_bb } };

        float A[3][3];
#pragma unroll
        for (int j = 0; j < 3; j++)
#pragma unroll
            for (int c = 0; c < 3; c++)
                A[j][c] = inv[j][0] * cov[0][c] + inv[j][1] * cov[1][c] + inv[j][2] * cov[2][c];

        float bb_[3];
#pragma unroll
        for (int c = 0; c < 3; c++)
            bb_[c] = mp[c] - A[0][c] * mI[0] - A[1][c] * mI[1] - A[2][c] * mI[2];

        float* outp = ab + (size_t)b * 12 * LOPLANE + wly * HLO + wlx;
#pragma unroll
        for (int j = 0; j < 3; j++)
#pragma unroll
            for (int c = 0; c < 3; c++)
                outp[(j * 3 + c) * LOPLANE] = A[j][c];
#pragma unroll
        for (int c = 0; c < 3; c++)
            outp[(9 + c) * LOPLANE] = bb_[c];
    }
}

// ---------------- Stage 3: bilinear upsample of A,b + apply to guide --------
__global__ __launch_bounds__(256) void gf_apply_kernel(
    const float* __restrict__ guide, const float* __restrict__ ab,
    float* __restrict__ out)
{
    int idx = blockIdx.x * 256 + threadIdx.x;   // 8 * 1024 * 1024 threads
    int b   = idx >> 20;
    int rem = idx & ((1 << 20) - 1);
    int y   = rem >> 10;
    int x   = rem & 1023;

    const float scale = 62.0f / 1023.0f;
    float ty = (float)y * scale;
    float tx = (float)x * scale;
    int y0 = (int)ty;  if (y0 > 61) y0 = 61;
    int x0 = (int)tx;  if (x0 > 61) x0 = 61;
    int y1 = y0 + 1;
    int x1 = x0 + 1;
    float wy = ty - (float)y0;
    float wx = tx - (float)x0;

    const float* abb = ab + (size_t)b * 12 * LOPLANE;
    int i00 = y0 * HLO + x0;
    int i01 = y0 * HLO + x1;
    int i10 = y1 * HLO + x0;
    int i11 = y1 * HLO + x1;

    float Av[12];
#pragma unroll
    for (int j = 0; j < 12; j++) {
        const float* p = abb + j * LOPLANE;
        float a00 = p[i00], a01 = p[i01], a10 = p[i10], a11 = p[i11];
        float r0 = a00 * (1.f - wy) + a10 * wy;
        float r1 = a01 * (1.f - wy) + a11 * wy;
        Av[j] = r0 * (1.f - wx) + r1 * wx;
    }

    const size_t plane = (size_t)HFULL * HFULL;
    size_t goff = (size_t)b * 3 * plane + ((size_t)y << 10) + x;
    float gr = guide[goff];
    float gg = guide[goff + plane];
    float gb = guide[goff + 2 * plane];

#pragma unroll
    for (int c = 0; c < 3; c++) {
        float v = Av[0 + c] * gr + Av[3 + c] * gg + Av[6 + c] * gb + Av[9 + c];
        out[goff + (size_t)c * plane] = v;
    }
}

extern "C" void kernel_launch(void* const* d_in, const int* in_sizes, int n_in,
                              void* d_out, int out_size, void* d_ws, size_t ws_size,
                              hipStream_t stream) {
    const float* guide = (const float*)d_in[0];
    const float* src   = (const float*)d_in[1];
    const float* w1    = (const float*)d_in[2];
    // d_in[3] = w3 is all-ones; box3 == plain window sum.
    float* out = (float*)d_out;
    float* ab  = (float*)d_ws;   // 8*12*3969*4 = 1.52 MB

    const int B = 8;
    int nblocks_stats = B * TILE * TILE;          // 8192
    gf_stats2<<<nblocks_stats, 256, 0, stream>>>(guide, src, w1, ab);

    int nblocks_apply = (B * HFULL * HFULL) / 256; // 32768
    gf_apply_kernel<<<nblocks_apply, 256, 0, stream>>>(guide, ab, out);
}

// Round 3
// 102.843 us; speedup vs baseline: 2.4356x; 2.4180x over previous
//
#include <hip/hip_runtime.h>

#define HLO 63            // (1024-32)/16+1
#define HFULL 1024
#define GF_EPS 1e-4f
#define LOPLANE (HLO*HLO) // 3969
#define NQ 64             // 16-row strips / 16-col groups per image
#define NSTAT 40          // 15 ones-sums + 24 w1-quadrant sums + N

// ---------------- Stage A: vertical strip sums per column -------------------
// grid: 8 * 64 * 4 blocks of 256 threads. Block = (b, qy, 256-column chunk).
// Each thread owns one column x, sums 16 rows of strip qy.
// hs layout: [b][qy][NSTAT][64]  (k = x>>4 innermost, coalesced)
__global__ __launch_bounds__(256) void gf_vstats(
    const float* __restrict__ guide, const float* __restrict__ src,
    const float* __restrict__ w1, float* __restrict__ hs)
{
    __shared__ float w1s[1024];

    int bid = blockIdx.x;
    int xc = bid & 3;
    int qy = (bid >> 2) & 63;
    int b  = bid >> 8;
    int tid = threadIdx.x;
    int x = xc * 256 + tid;
    int xin = x & 15;

    reinterpret_cast<float4*>(w1s)[tid] = reinterpret_cast<const float4*>(w1)[tid];
    __syncthreads();

    const size_t plane = (size_t)HFULL * HFULL;
    const float* g0 = guide + (size_t)b * 3 * plane;
    const float* s0 = src   + (size_t)b * 3 * plane;

    float acc[NSTAT];
#pragma unroll
    for (int i = 0; i < NSTAT; i++) acc[i] = 0.f;

#pragma unroll
    for (int yin = 0; yin < 16; ++yin) {
        size_t off = (size_t)(qy * 16 + yin) * HFULL + x;
        float gr = g0[off];
        float gg = g0[plane + off];
        float gb = g0[2 * plane + off];
        float pr = s0[off];
        float pg = s0[plane + off];
        float pb = s0[2 * plane + off];
        // the four w1 sub-kernel taps for this (yin, xin): v=row-half, h=col-half
        float w00 = w1s[yin * 32 + xin];
        float w01 = w1s[yin * 32 + 16 + xin];
        float w10 = w1s[(16 + yin) * 32 + xin];
        float w11 = w1s[(16 + yin) * 32 + 16 + xin];

        acc[0] += gr;  acc[1] += gg;  acc[2] += gb;
        acc[3] += pr;  acc[4] += pg;  acc[5] += pb;
        acc[6]  += gr * pr;  acc[7]  += gr * pg;  acc[8]  += gr * pb;
        acc[9]  += gg * pr;  acc[10] += gg * pg;  acc[11] += gg * pb;
        acc[12] += gb * pr;  acc[13] += gb * pg;  acc[14] += gb * pb;

        float rr = gr * gr, rg = gr * gg, rb = gr * gb;
        float g2 = gg * gg, gb2 = gg * gb, b2 = gb * gb;
        acc[15] += w00 * rr;  acc[16] += w01 * rr;  acc[17] += w10 * rr;  acc[18] += w11 * rr;
        acc[19] += w00 * rg;  acc[20] += w01 * rg;  acc[21] += w10 * rg;  acc[22] += w11 * rg;
        acc[23] += w00 * rb;  acc[24] += w01 * rb;  acc[25] += w10 * rb;  acc[26] += w11 * rb;
        acc[27] += w00 * g2;  acc[28] += w01 * g2;  acc[29] += w10 * g2;  acc[30] += w11 * g2;
        acc[31] += w00 * gb2; acc[32] += w01 * gb2; acc[33] += w10 * gb2; acc[34] += w11 * gb2;
        acc[35] += w00 * b2;  acc[36] += w01 * b2;  acc[37] += w10 * b2;  acc[38] += w11 * b2;
        acc[39] += w00 + w01 + w10 + w11;   // -> sum(w1) after 16-lane reduce
    }

    // reduce across each 16-lane group (16 consecutive columns = one k-group)
#pragma unroll
    for (int m = 1; m <= 8; m <<= 1) {
#pragma unroll
        for (int i = 0; i < NSTAT; i++)
            acc[i] += __shfl_xor(acc[i], m, 64);
    }

    int lane = tid & 63;
    if ((lane & 15) == 0) {
        int k = x >> 4;
        float* hp = hs + (((size_t)b * NQ + qy) * NSTAT) * 64 + k;
#pragma unroll
        for (int i = 0; i < NSTAT; i++)
            hp[i * 64] = acc[i];
    }
}

// ---------------- Stage C: assemble windows + 3x3 inverse -> A,b planes -----
// thread per window (b, ly, lx). Corner combination of hs.
__global__ __launch_bounds__(256) void gf_solve(
    const float* __restrict__ hs, float* __restrict__ ab)
{
    int idx = blockIdx.x * 256 + threadIdx.x;
    if (idx >= 8 * LOPLANE) return;
    int lx = idx % HLO;
    int t  = idx / HLO;
    int ly = t % HLO;
    int b  = t / HLO;

    const float* h0 = hs + ((size_t)b * NQ + ly) * NSTAT * 64;  // strip qy=ly   (v=0)
    const float* h1 = h0 + (size_t)NSTAT * 64;                  // strip qy=ly+1 (v=1)

    float s[15];
#pragma unroll
    for (int i = 0; i < 15; i++)
        s[i] = h0[i * 64 + lx] + h0[i * 64 + lx + 1]
             + h1[i * 64 + lx] + h1[i * 64 + lx + 1];

    float v[6];
#pragma unroll
    for (int p = 0; p < 6; p++) {
        int base = 15 + p * 4;
        v[p] = h0[(base + 0) * 64 + lx]     // v0 h0: top-left
             + h0[(base + 1) * 64 + lx + 1] // v0 h1: top-right
             + h1[(base + 2) * 64 + lx]     // v1 h0: bottom-left
             + h1[(base + 3) * 64 + lx + 1];// v1 h1: bottom-right
    }
    float N = h0[39 * 64 + lx];

    float inv_n = 1.f / N;
    float mI[3] = { s[0] * inv_n, s[1] * inv_n, s[2] * inv_n };
    float mp[3] = { s[3] * inv_n, s[4] * inv_n, s[5] * inv_n };

    float cov[3][3];
#pragma unroll
    for (int i = 0; i < 3; i++)
#pragma unroll
        for (int c = 0; c < 3; c++)
            cov[i][c] = s[6 + i * 3 + c] * inv_n - mI[i] * mp[c];

    float v_rr = v[0] * inv_n - mI[0] * mI[0] + GF_EPS;
    float v_rg = v[1] * inv_n - mI[0] * mI[1];
    float v_rb = v[2] * inv_n - mI[0] * mI[2];
    float v_gg = v[3] * inv_n - mI[1] * mI[1] + GF_EPS;
    float v_gb = v[4] * inv_n - mI[1] * mI[2];
    float v_bb = v[5] * inv_n - mI[2] * mI[2] + GF_EPS;

    float det = v_rr * v_gg * v_bb + v_rg * v_gb * v_rb + v_rb * v_rg * v_gb
              - v_rb * v_gg * v_rb - v_rg * v_rg * v_bb - v_rr * v_gb * v_gb;
    float invdet = 1.f / det;

    float i_rr =  (v_gg * v_bb - v_gb * v_gb) * invdet;
    float i_rg = -(v_rg * v_bb - v_rb * v_gb) * invdet;
    float i_rb =  (v_rg * v_gb - v_rb * v_gg) * invdet;
    float i_gg =  (v_rr * v_bb - v_rb * v_rb) * invdet;
    float i_gb = -(v_rr * v_gb - v_rb * v_rg) * invdet;
    float i_bb =  (v_rr * v_gg - v_rg * v_rg) * invdet;

    float inv[3][3] = { { i_rr, i_rg, i_rb },
                        { i_rg, i_gg, i_gb },
                        { i_rb, i_gb, i_bb } };

    float A[3][3];
#pragma unroll
    for (int j = 0; j < 3; j++)
#pragma unroll
        for (int c = 0; c < 3; c++)
            A[j][c] = inv[j][0] * cov[0][c] + inv[j][1] * cov[1][c] + inv[j][2] * cov[2][c];

    float bb_[3];
#pragma unroll
    for (int c = 0; c < 3; c++)
        bb_[c] = mp[c] - A[0][c] * mI[0] - A[1][c] * mI[1] - A[2][c] * mI[2];

    float* outp = ab + (size_t)b * 12 * LOPLANE + ly * HLO + lx;
#pragma unroll
    for (int j = 0; j < 3; j++)
#pragma unroll
        for (int c = 0; c < 3; c++)
            outp[(j * 3 + c) * LOPLANE] = A[j][c];
#pragma unroll
    for (int c = 0; c < 3; c++)
        outp[(9 + c) * LOPLANE] = bb_[c];
}

// ---------------- Stage 3: bilinear upsample of A,b + apply to guide --------
__global__ __launch_bounds__(256) void gf_apply_kernel(
    const float* __restrict__ guide, const float* __restrict__ ab,
    float* __restrict__ out)
{
    int idx = blockIdx.x * 256 + threadIdx.x;   // 8 * 1024 * 1024 threads
    int b   = idx >> 20;
    int rem = idx & ((1 << 20) - 1);
    int y   = rem >> 10;
    int x   = rem & 1023;

    const float scale = 62.0f / 1023.0f;
    float ty = (float)y * scale;
    float tx = (float)x * scale;
    int y0 = (int)ty;  if (y0 > 61) y0 = 61;
    int x0 = (int)tx;  if (x0 > 61) x0 = 61;
    int y1 = y0 + 1;
    int x1 = x0 + 1;
    float wy = ty - (float)y0;
    float wx = tx - (float)x0;

    const float* abb = ab + (size_t)b * 12 * LOPLANE;
    int i00 = y0 * HLO + x0;
    int i01 = y0 * HLO + x1;
    int i10 = y1 * HLO + x0;
    int i11 = y1 * HLO + x1;

    float Av[12];
#pragma unroll
    for (int j = 0; j < 12; j++) {
        const float* p = abb + j * LOPLANE;
        float a00 = p[i00], a01 = p[i01], a10 = p[i10], a11 = p[i11];
        float r0 = a00 * (1.f - wy) + a10 * wy;
        float r1 = a01 * (1.f - wy) + a11 * wy;
        Av[j] = r0 * (1.f - wx) + r1 * wx;
    }

    const size_t plane = (size_t)HFULL * HFULL;
    size_t goff = (size_t)b * 3 * plane + ((size_t)y << 10) + x;
    float gr = guide[goff];
    float gg = guide[goff + plane];
    float gb = guide[goff + 2 * plane];

#pragma unroll
    for (int c = 0; c < 3; c++) {
        float v = Av[0 + c] * gr + Av[3 + c] * gg + Av[6 + c] * gb + Av[9 + c];
        out[goff + (size_t)c * plane] = v;
    }
}

extern "C" void kernel_launch(void* const* d_in, const int* in_sizes, int n_in,
                              void* d_out, int out_size, void* d_ws, size_t ws_size,
                              hipStream_t stream) {
    const float* guide = (const float*)d_in[0];
    const float* src   = (const float*)d_in[1];
    const float* w1    = (const float*)d_in[2];
    // d_in[3] = w3 is all-ones; box3 == plain window sum.
    float* out = (float*)d_out;

    float* ab = (float*)d_ws;                         // 1.53 MB
    float* hs = (float*)((char*)d_ws + (2 << 20));    // 5.25 MB  ([8][64][40][64])

    gf_vstats<<<8 * NQ * 4, 256, 0, stream>>>(guide, src, w1, hs);

    int nthr = 8 * LOPLANE;
    gf_solve<<<(nthr + 255) / 256, 256, 0, stream>>>(hs, ab);

    gf_apply_kernel<<<(8 * HFULL * HFULL) / 256, 256, 0, stream>>>(guide, ab, out);
}

// Round 4
// 97.803 us; speedup vs baseline: 2.5611x; 1.0515x over previous
//
#include <hip/hip_runtime.h>

#define HLO 63            // (1024-32)/16+1
#define HFULL 1024
#define GF_EPS 1e-4f
#define LOPLANE (HLO*HLO) // 3969
#define NQ 64             // 16-row strips per image
#define NSTAT 40          // 15 ones-sums + 24 w1-quadrant sums + sum(w1)

// quad-level (4-lane) butterfly add via DPP quad_perm — pure VALU, no DS pipe
template<int CTRL>
__device__ __forceinline__ float dppadd(float v) {
    int r = __builtin_amdgcn_update_dpp(0, __float_as_int(v), CTRL, 0xF, 0xF, false);
    return v + __int_as_float(r);
}

// ---------------- Stage A: half-strip (8-row) sums per 16-col group ---------
// grid: 8 * 64 * 2 blocks of 256 threads. Block = (b, strip qy, half h).
// Thread t owns columns 4t..4t+3 over 8 rows; quad of threads = one k-group.
// hs layout: [b][qy][h][NSTAT][64]  (k innermost, coalesced for solve)
__global__ __launch_bounds__(256, 4) void gf_vstats(
    const float* __restrict__ guide, const float* __restrict__ src,
    const float* __restrict__ w1, float* __restrict__ hs)
{
    __shared__ float w1s[1024];

    int bid = blockIdx.x;
    int h  = bid & 1;
    int qy = (bid >> 1) & 63;
    int b  = bid >> 7;
    int tid = threadIdx.x;

    reinterpret_cast<float4*>(w1s)[tid] = reinterpret_cast<const float4*>(w1)[tid];
    __syncthreads();

    const size_t plane = (size_t)HFULL * HFULL;
    const size_t rowoff = (size_t)(qy * 16 + h * 8) * HFULL + 4 * tid;
    const float* g0 = guide + (size_t)b * 3 * plane + rowoff;
    const float* s0 = src   + (size_t)b * 3 * plane + rowoff;

    int xq = tid & 3;                       // position of this quad in its group
    const float* wrow = &w1s[(h * 8) * 32 + 4 * xq];

    float acc[NSTAT];
#pragma unroll
    for (int i = 0; i < NSTAT; i++) acc[i] = 0.f;

#pragma unroll
    for (int r = 0; r < 8; ++r) {
        size_t off = (size_t)r * HFULL;
        float4 vgr = *reinterpret_cast<const float4*>(g0 + off);
        float4 vgg = *reinterpret_cast<const float4*>(g0 + plane + off);
        float4 vgb = *reinterpret_cast<const float4*>(g0 + 2 * plane + off);
        float4 vpr = *reinterpret_cast<const float4*>(s0 + off);
        float4 vpg = *reinterpret_cast<const float4*>(s0 + plane + off);
        float4 vpb = *reinterpret_cast<const float4*>(s0 + 2 * plane + off);
        float4 w00 = *reinterpret_cast<const float4*>(wrow + r * 32);
        float4 w01 = *reinterpret_cast<const float4*>(wrow + r * 32 + 16);
        float4 w10 = *reinterpret_cast<const float4*>(wrow + r * 32 + 512);
        float4 w11 = *reinterpret_cast<const float4*>(wrow + r * 32 + 512 + 16);

        const float* grf = reinterpret_cast<const float*>(&vgr);
        const float* ggf = reinterpret_cast<const float*>(&vgg);
        const float* gbf = reinterpret_cast<const float*>(&vgb);
        const float* prf = reinterpret_cast<const float*>(&vpr);
        const float* pgf = reinterpret_cast<const float*>(&vpg);
        const float* pbf = reinterpret_cast<const float*>(&vpb);
        const float* w00f = reinterpret_cast<const float*>(&w00);
        const float* w01f = reinterpret_cast<const float*>(&w01);
        const float* w10f = reinterpret_cast<const float*>(&w10);
        const float* w11f = reinterpret_cast<const float*>(&w11);

#pragma unroll
        for (int j = 0; j < 4; ++j) {
            float Gr = grf[j], Gg = ggf[j], Gb = gbf[j];
            float Pr = prf[j], Pg = pgf[j], Pb = pbf[j];
            float W00 = w00f[j], W01 = w01f[j], W10 = w10f[j], W11 = w11f[j];

            acc[0] += Gr;  acc[1] += Gg;  acc[2] += Gb;
            acc[3] += Pr;  acc[4] += Pg;  acc[5] += Pb;
            acc[6]  += Gr * Pr;  acc[7]  += Gr * Pg;  acc[8]  += Gr * Pb;
            acc[9]  += Gg * Pr;  acc[10] += Gg * Pg;  acc[11] += Gg * Pb;
            acc[12] += Gb * Pr;  acc[13] += Gb * Pg;  acc[14] += Gb * Pb;

            float RR = Gr * Gr, RG = Gr * Gg, RB = Gr * Gb;
            float GG = Gg * Gg, GB = Gg * Gb, BB = Gb * Gb;
            acc[15] += W00 * RR;  acc[16] += W01 * RR;  acc[17] += W10 * RR;  acc[18] += W11 * RR;
            acc[19] += W00 * RG;  acc[20] += W01 * RG;  acc[21] += W10 * RG;  acc[22] += W11 * RG;
            acc[23] += W00 * RB;  acc[24] += W01 * RB;  acc[25] += W10 * RB;  acc[26] += W11 * RB;
            acc[27] += W00 * GG;  acc[28] += W01 * GG;  acc[29] += W10 * GG;  acc[30] += W11 * GG;
            acc[31] += W00 * GB;  acc[32] += W01 * GB;  acc[33] += W10 * GB;  acc[34] += W11 * GB;
            acc[35] += W00 * BB;  acc[36] += W01 * BB;  acc[37] += W10 * BB;  acc[38] += W11 * BB;
            acc[39] += (W00 + W01) + (W10 + W11);
        }
    }

    // reduce across the 4 lanes of each quad (one 16-col group): DPP, no DS
#pragma unroll
    for (int i = 0; i < NSTAT; i++) {
        acc[i] = dppadd<0xB1>(acc[i]);   // quad_perm [1,0,3,2]  (xor 1)
        acc[i] = dppadd<0x4E>(acc[i]);   // quad_perm [2,3,0,1]  (xor 2)
    }

    if ((tid & 3) == 0) {
        int k = tid >> 2;
        float* hp = hs + ((((size_t)b * NQ + qy) * 2 + h) * NSTAT) * 64 + k;
#pragma unroll
        for (int i = 0; i < NSTAT; i++)
            hp[i * 64] = acc[i];
    }
}

// ---------------- Stage C: assemble windows + 3x3 inverse -> A,b planes -----
__global__ __launch_bounds__(256) void gf_solve(
    const float* __restrict__ hs, float* __restrict__ ab)
{
    int idx = blockIdx.x * 256 + threadIdx.x;
    if (idx >= 8 * LOPLANE) return;
    int lx = idx % HLO;
    int t  = idx / HLO;
    int ly = t % HLO;
    int b  = t / HLO;

    const float* h00 = hs + (((size_t)b * NQ + ly) * 2) * NSTAT * 64; // strip ly, half 0
    const float* h01 = h00 + (size_t)NSTAT * 64;                      // strip ly, half 1
    const float* h10 = h00 + (size_t)2 * NSTAT * 64;                  // strip ly+1, half 0
    const float* h11 = h00 + (size_t)3 * NSTAT * 64;

    float s[15];
#pragma unroll
    for (int i = 0; i < 15; i++) {
        int o0 = i * 64 + lx;
        s[i] = (h00[o0] + h01[o0] + h10[o0] + h11[o0])
             + (h00[o0 + 1] + h01[o0 + 1] + h10[o0 + 1] + h11[o0 + 1]);
    }

    float v[6];
#pragma unroll
    for (int p = 0; p < 6; p++) {
        int base = 15 + p * 4;
        v[p] = (h00[(base + 0) * 64 + lx]     + h01[(base + 0) * 64 + lx])      // top-left
             + (h00[(base + 1) * 64 + lx + 1] + h01[(base + 1) * 64 + lx + 1])  // top-right
             + (h10[(base + 2) * 64 + lx]     + h11[(base + 2) * 64 + lx])      // bottom-left
             + (h10[(base + 3) * 64 + lx + 1] + h11[(base + 3) * 64 + lx + 1]); // bottom-right
    }
    float N = h00[39 * 64 + lx] + h01[39 * 64 + lx];

    float inv_n = 1.f / N;
    float mI[3] = { s[0] * inv_n, s[1] * inv_n, s[2] * inv_n };
    float mp[3] = { s[3] * inv_n, s[4] * inv_n, s[5] * inv_n };

    float cov[3][3];
#pragma unroll
    for (int i = 0; i < 3; i++)
#pragma unroll
        for (int c = 0; c < 3; c++)
            cov[i][c] = s[6 + i * 3 + c] * inv_n - mI[i] * mp[c];

    float v_rr = v[0] * inv_n - mI[0] * mI[0] + GF_EPS;
    float v_rg = v[1] * inv_n - mI[0] * mI[1];
    float v_rb = v[2] * inv_n - mI[0] * mI[2];
    float v_gg = v[3] * inv_n - mI[1] * mI[1] + GF_EPS;
    float v_gb = v[4] * inv_n - mI[1] * mI[2];
    float v_bb = v[5] * inv_n - mI[2] * mI[2] + GF_EPS;

    float det = v_rr * v_gg * v_bb + v_rg * v_gb * v_rb + v_rb * v_rg * v_gb
              - v_rb * v_gg * v_rb - v_rg * v_rg * v_bb - v_rr * v_gb * v_gb;
    float invdet = 1.f / det;

    float i_rr =  (v_gg * v_bb - v_gb * v_gb) * invdet;
    float i_rg = -(v_rg * v_bb - v_rb * v_gb) * invdet;
    float i_rb =  (v_rg * v_gb - v_rb * v_gg) * invdet;
    float i_gg =  (v_rr * v_bb - v_rb * v_rb) * invdet;
    float i_gb = -(v_rr * v_gb - v_rb * v_rg) * invdet;
    float i_bb =  (v_rr * v_gg - v_rg * v_rg) * invdet;

    float inv[3][3] = { { i_rr, i_rg, i_rb },
                        { i_rg, i_gg, i_gb },
                        { i_rb, i_gb, i_bb } };

    float A[3][3];
#pragma unroll
    for (int j = 0; j < 3; j++)
#pragma unroll
        for (int c = 0; c < 3; c++)
            A[j][c] = inv[j][0] * cov[0][c] + inv[j][1] * cov[1][c] + inv[j][2] * cov[2][c];

    float bb_[3];
#pragma unroll
    for (int c = 0; c < 3; c++)
        bb_[c] = mp[c] - A[0][c] * mI[0] - A[1][c] * mI[1] - A[2][c] * mI[2];

    float* outp = ab + (size_t)b * 12 * LOPLANE + ly * HLO + lx;
#pragma unroll
    for (int j = 0; j < 3; j++)
#pragma unroll
        for (int c = 0; c < 3; c++)
            outp[(j * 3 + c) * LOPLANE] = A[j][c];
#pragma unroll
    for (int c = 0; c < 3; c++)
        outp[(9 + c) * LOPLANE] = bb_[c];
}

// ---------------- Stage 3: bilinear upsample of A,b + apply to guide --------
// block = one output row (b, y); y-lerp hoisted to LDS; thread = 4 px float4.
__global__ __launch_bounds__(256) void gf_apply(
    const float* __restrict__ guide, const float* __restrict__ ab,
    float* __restrict__ out)
{
    __shared__ float rl[12][64];   // y-lerped row of each plane (63 used)

    int bid = blockIdx.x;          // 8 * 1024
    int y = bid & 1023;
    int b = bid >> 10;
    int tid = threadIdx.x;

    const float scale = 62.0f / 1023.0f;
    float ty = (float)y * scale;
    int y0 = (int)ty;  if (y0 > 61) y0 = 61;
    float wy = ty - (float)y0;

    const float* abb = ab + (size_t)b * 12 * LOPLANE;
    for (int i = tid; i < 12 * 63; i += 256) {
        int p = i / 63, c = i - p * 63;
        const float* pp = abb + (size_t)p * LOPLANE + y0 * HLO + c;
        rl[p][c] = pp[0] * (1.f - wy) + pp[HLO] * wy;
    }
    __syncthreads();

    int x = 4 * tid;
    float t0 = (float)x * scale;
    int c0 = (int)t0;  if (c0 > 61) c0 = 61;

    bool  sel[4];
    float wx[4];
#pragma unroll
    for (int j = 0; j < 4; ++j) {
        float t = (float)(x + j) * scale;
        int x0 = (int)t;  if (x0 > 61) x0 = 61;
        sel[j] = (x0 > c0);
        wx[j]  = t - (float)x0;
    }

    float Av[12][4];
#pragma unroll
    for (int p = 0; p < 12; ++p) {
        float r0 = rl[p][c0], r1 = rl[p][c0 + 1], r2 = rl[p][c0 + 2];
#pragma unroll
        for (int j = 0; j < 4; ++j) {
            float a  = sel[j] ? r1 : r0;
            float bb = sel[j] ? r2 : r1;
            Av[p][j] = a + (bb - a) * wx[j];
        }
    }

    const size_t plane = (size_t)HFULL * HFULL;
    size_t goff = (size_t)b * 3 * plane + ((size_t)y << 10) + x;
    float4 vgr = *reinterpret_cast<const float4*>(guide + goff);
    float4 vgg = *reinterpret_cast<const float4*>(guide + goff + plane);
    float4 vgb = *reinterpret_cast<const float4*>(guide + goff + 2 * plane);
    const float* grf = reinterpret_cast<const float*>(&vgr);
    const float* ggf = reinterpret_cast<const float*>(&vgg);
    const float* gbf = reinterpret_cast<const float*>(&vgb);

#pragma unroll
    for (int c = 0; c < 3; ++c) {
        float4 o;
        float* of = reinterpret_cast<float*>(&o);
#pragma unroll
        for (int j = 0; j < 4; ++j)
            of[j] = Av[0 + c][j] * grf[j] + Av[3 + c][j] * ggf[j]
                  + Av[6 + c][j] * gbf[j] + Av[9 + c][j];
        *reinterpret_cast<float4*>(out + goff + (size_t)c * plane) = o;
    }
}

extern "C" void kernel_launch(void* const* d_in, const int* in_sizes, int n_in,
                              void* d_out, int out_size, void* d_ws, size_t ws_size,
                              hipStream_t stream) {
    const float* guide = (const float*)d_in[0];
    const float* src   = (const float*)d_in[1];
    const float* w1    = (const float*)d_in[2];
    // d_in[3] = w3 is all-ones; box3 == plain window sum.
    float* out = (float*)d_out;

    float* ab = (float*)d_ws;                         // 1.53 MB
    float* hs = (float*)((char*)d_ws + (2 << 20));    // 10.5 MB: [8][64][2][40][64]

    gf_vstats<<<8 * NQ * 2, 256, 0, stream>>>(guide, src, w1, hs);

    int nthr = 8 * LOPLANE;
    gf_solve<<<(nthr + 255) / 256, 256, 0, stream>>>(hs, ab);

    gf_apply<<<8 * 1024, 256, 0, stream>>>(guide, ab, out);
}